// Round 1
// baseline (20426.982 us; speedup 1.0000x reference)
//
#include <hip/hip_runtime.h>

#define Bn 64
#define Sn 512
#define Fn 64
#define Hn 512
#define Un 128
#define Tn 96

__device__ __forceinline__ float sigm(float x) {
    return 1.0f / (1.0f + __expf(-x));
}
__device__ __forceinline__ float tanh_f(float x) {
    x = fminf(fmaxf(x, -15.0f), 15.0f);
    float e = __expf(2.0f * x);
    return (e - 1.0f) / (e + 1.0f);
}

// ---------------- setup kernels (run every call; ws is re-poisoned) ----------------
__global__ __launch_bounds__(256) void k_transpose_x(const float* __restrict__ x, float* __restrict__ xT) {
    int t = blockIdx.x * 256 + threadIdx.x;             // 2,097,152 = B*S*F
    int f = t & 63, s = (t >> 6) & 511, b = t >> 15;
    xT[(s * Fn + f) * Bn + b] = x[t];                   // xT[s][f][b]
}
__global__ __launch_bounds__(256) void k_transpose_w2(const float* __restrict__ W2, float* __restrict__ W2T) {
    int t = blockIdx.x * 256 + threadIdx.x;             // 65,536 = U*H
    int u = t >> 9, j = t & 511;
    W2T[j * Un + u] = W2[t];                            // W2T[j][u]
}
__global__ __launch_bounds__(256) void k_transpose_dec(const float* __restrict__ dW, float* __restrict__ WiT,
                                                       float* __restrict__ WgT, float* __restrict__ WoT) {
    int t = blockIdx.x * 256 + threadIdx.x;             // 262,144 = H*H ; dec_Wih rows have length 513
    int j = t & 511, j2 = t >> 9;
    WiT[t] = dW[(j)        * 513 + j2];                 // WiT[j2][j], gate i (rows 0..511)
    WgT[t] = dW[(1024 + j) * 513 + j2];                 // gate g (rows 1024..1535)
    WoT[t] = dW[(1536 + j) * 513 + j2];                 // gate o (rows 1536..2047)
}
__global__ __launch_bounds__(256) void k_zero(float* __restrict__ h0, float* __restrict__ cst) {
    int t = blockIdx.x * 256 + threadIdx.x;             // 65,536
    if (t < Hn * Bn) h0[t] = 0.0f; else cst[t - Hn * Bn] = 0.0f;
}

// ---------------- encoder: one launch per time step ----------------
// grid 256 x 256: block owns 2 hidden cols j, threads = (jl, khalf, b); K split in halves.
__global__ __launch_bounds__(256)
void enc_step_k(const float* __restrict__ xT, const float* __restrict__ Wih,
                const float* __restrict__ Whh, const float* __restrict__ bih,
                const float* __restrict__ bhh, const float* __restrict__ hprev,
                float* __restrict__ hnext, float* __restrict__ cst,
                float* __restrict__ enc, int t)
{
    __shared__ float red[2 * 4 * 64];
    const int b  = threadIdx.x & 63;
    const int kh = (threadIdx.x >> 6) & 1;
    const int jl = threadIdx.x >> 7;
    const int j  = blockIdx.x * 2 + jl;

    float ai = 0.f, af = 0.f, ag = 0.f, ao = 0.f;
    // fused input GEMM: x(t) . Wih rows (F=64, split 32/32)
    {
        const float* xr  = xT + (t * Fn + kh * 32) * Bn + b;
        const float* wiX = Wih + (0 * Hn + j) * Fn + kh * 32;
        const float* wfX = Wih + (1 * Hn + j) * Fn + kh * 32;
        const float* wgX = Wih + (2 * Hn + j) * Fn + kh * 32;
        const float* woX = Wih + (3 * Hn + j) * Fn + kh * 32;
        #pragma unroll
        for (int f = 0; f < 32; f += 4) {
            float4 wi = *(const float4*)(wiX + f);
            float4 wf = *(const float4*)(wfX + f);
            float4 wg = *(const float4*)(wgX + f);
            float4 wo = *(const float4*)(woX + f);
            float x0 = xr[(f+0)*Bn], x1 = xr[(f+1)*Bn], x2 = xr[(f+2)*Bn], x3 = xr[(f+3)*Bn];
            ai += wi.x*x0 + wi.y*x1 + wi.z*x2 + wi.w*x3;
            af += wf.x*x0 + wf.y*x1 + wf.z*x2 + wf.w*x3;
            ag += wg.x*x0 + wg.y*x1 + wg.z*x2 + wg.w*x3;
            ao += wo.x*x0 + wo.y*x1 + wo.z*x2 + wo.w*x3;
        }
    }
    // recurrent GEMM: h(t-1) . Whh rows (K=512, split 256/256)
    {
        const float* hp  = hprev + (kh * 256) * Bn + b;
        const float* wiH = Whh + (0 * Hn + j) * Hn + kh * 256;
        const float* wfH = Whh + (1 * Hn + j) * Hn + kh * 256;
        const float* wgH = Whh + (2 * Hn + j) * Hn + kh * 256;
        const float* woH = Whh + (3 * Hn + j) * Hn + kh * 256;
        #pragma unroll 2
        for (int k = 0; k < 256; k += 4) {
            float4 wi = *(const float4*)(wiH + k);
            float4 wf = *(const float4*)(wfH + k);
            float4 wg = *(const float4*)(wgH + k);
            float4 wo = *(const float4*)(woH + k);
            float h0 = hp[(k+0)*Bn], h1 = hp[(k+1)*Bn], h2 = hp[(k+2)*Bn], h3 = hp[(k+3)*Bn];
            ai += wi.x*h0 + wi.y*h1 + wi.z*h2 + wi.w*h3;
            af += wf.x*h0 + wf.y*h1 + wf.z*h2 + wf.w*h3;
            ag += wg.x*h0 + wg.y*h1 + wg.z*h2 + wg.w*h3;
            ao += wo.x*h0 + wo.y*h1 + wo.z*h2 + wo.w*h3;
        }
    }
    if (kh) {
        red[(jl*4+0)*64 + b] = ai;
        red[(jl*4+1)*64 + b] = af;
        red[(jl*4+2)*64 + b] = ag;
        red[(jl*4+3)*64 + b] = ao;
    }
    __syncthreads();
    if (!kh) {
        ai += red[(jl*4+0)*64+b] + bih[j]        + bhh[j];
        af += red[(jl*4+1)*64+b] + bih[Hn+j]     + bhh[Hn+j];
        ag += red[(jl*4+2)*64+b] + bih[2*Hn+j]   + bhh[2*Hn+j];
        ao += red[(jl*4+3)*64+b] + bih[3*Hn+j]   + bhh[3*Hn+j];
        float ig = sigm(ai), fg = sigm(af), gg = tanh_f(ag), og = sigm(ao);
        float cn = fg * cst[j*Bn+b] + ig * gg;
        float hn = og * tanh_f(cn);
        cst[j*Bn+b]  = cn;
        hnext[j*Bn+b] = hn;
        enc[(t*Hn + j)*Bn + b] = hn;                     // enc[s][j][b]
    }
}

// ---------------- w2_enc = enc_out . W2^T + b2  (one big GEMM) ----------------
// grid 512 (one block per s) x 256 threads; LDS-staged enc tile; 32 accumulators/thread.
__global__ __launch_bounds__(256)
void w2enc_k(const float* __restrict__ enc, const float* __restrict__ W2T,
             const float* __restrict__ b2, float* __restrict__ w2e)
{
    __shared__ float tile[64 * 64];
    const int s = blockIdx.x;
    const int tid = threadIdx.x;
    const int u = tid & 127, bq = tid >> 7;
    float acc[32];
    #pragma unroll
    for (int i = 0; i < 32; i++) acc[i] = 0.f;
    for (int jc = 0; jc < 8; jc++) {
        __syncthreads();
        #pragma unroll
        for (int r = 0; r < 16; r++) {
            int e = r * 256 + tid;
            tile[e] = enc[(s * Hn + jc * 64) * Bn + e];
        }
        __syncthreads();
        for (int jl = 0; jl < 64; jl++) {
            float wv = W2T[(jc * 64 + jl) * Un + u];
            const float4* trow = (const float4*)&tile[jl * 64 + bq * 32];
            #pragma unroll
            for (int i = 0; i < 8; i++) {
                float4 t4 = trow[i];
                acc[i*4+0] += t4.x * wv; acc[i*4+1] += t4.y * wv;
                acc[i*4+2] += t4.z * wv; acc[i*4+3] += t4.w * wv;
            }
        }
    }
    float bb = b2[u];
    #pragma unroll
    for (int i = 0; i < 32; i++)
        w2e[((bq * 32 + i) * Sn + s) * Un + u] = acc[i] + bb;   // w2e[b][s][u]
}

// ---------------- decoder step kernels ----------------
// K_A: w1h + scores + softmax, one block per batch element.
__global__ __launch_bounds__(256)
void dec_attn_k(const float* __restrict__ hatt, const float* __restrict__ W1,
                const float* __restrict__ b1, const float* __restrict__ Vv,
                const float* __restrict__ bV, const float* __restrict__ w2e,
                float* __restrict__ attnT)
{
    __shared__ float w1h[Un];
    __shared__ float Vs[Un];
    __shared__ float sc[Sn];
    __shared__ float red2[256];
    const int b = blockIdx.x;
    const int tid = threadIdx.x;
    if (tid < 128) Vs[tid] = Vv[tid];
    {   // w1h[u] = b1[u] + sum_k W1[u][k] * hatt[k][b]
        const int u = tid & 127, half = tid >> 7;
        const float* wr = W1 + u * Hn + half * 256;
        const float* hp = hatt + half * 256 * Bn + b;
        float a = 0.f;
        #pragma unroll 4
        for (int k = 0; k < 256; k++) a += wr[k] * hp[k * Bn];
        red2[tid] = a;
    }
    __syncthreads();
    if (tid < 128) w1h[tid] = red2[tid] + red2[tid + 128] + b1[tid];
    __syncthreads();
    const float bV0 = bV[0];
    {   // scores, 2 per thread
        const float* r0 = w2e + (b * Sn + tid) * Un;
        const float* r1 = r0 + 256 * Un;
        float a0 = 0.f, a1 = 0.f;
        #pragma unroll 4
        for (int u = 0; u < 128; u++) {
            float wv = w1h[u], vv = Vs[u];
            a0 += vv * tanh_f(wv + r0[u]);
            a1 += vv * tanh_f(wv + r1[u]);
        }
        sc[tid] = a0 + bV0;
        sc[tid + 256] = a1 + bV0;
    }
    __syncthreads();
    red2[tid] = fmaxf(sc[tid], sc[tid + 256]);
    __syncthreads();
    for (int w = 128; w > 0; w >>= 1) {
        if (tid < w) red2[tid] = fmaxf(red2[tid], red2[tid + w]);
        __syncthreads();
    }
    const float mx = red2[0];
    __syncthreads();
    float e0 = __expf(sc[tid] - mx);
    float e1 = __expf(sc[tid + 256] - mx);
    red2[tid] = e0 + e1;
    __syncthreads();
    for (int w = 128; w > 0; w >>= 1) {
        if (tid < w) red2[tid] += red2[tid + w];
        __syncthreads();
    }
    const float inv = 1.0f / red2[0];
    attnT[tid * Bn + b]         = e0 * inv;              // attnT[s][b]
    attnT[(tid + 256) * Bn + b] = e1 * inv;
}

// K_B: ctx[j][b] = sum_s attn[s][b] * enc[s][j][b]
__global__ __launch_bounds__(128)
void dec_ctx_k(const float* __restrict__ attnT, const float* __restrict__ enc,
               float* __restrict__ ctx)
{
    const int b = threadIdx.x & 63;
    const int j = blockIdx.x * 2 + (threadIdx.x >> 6);
    float a = 0.f;
    const float* ap = attnT + b;
    const float* ep = enc + j * Bn + b;
    #pragma unroll 4
    for (int s = 0; s < Sn; s++)
        a += ap[s * Bn] * ep[s * (Hn * Bn)];
    ctx[j * Bn + b] = a;
}

// K_C: decoder LSTM cell from zero state (only i,g,o gates matter; y_t = 0)
__global__ __launch_bounds__(128)
void dec_gate_k(const float* __restrict__ ctx, const float* __restrict__ WiT,
                const float* __restrict__ WgT, const float* __restrict__ WoT,
                const float* __restrict__ dbih, const float* __restrict__ dbhh,
                float* __restrict__ hdec)
{
    const int b = threadIdx.x & 63;
    const int j = blockIdx.x * 2 + (threadIdx.x >> 6);
    float ai = dbih[j]          + dbhh[j];
    float ag = dbih[2*Hn + j]   + dbhh[2*Hn + j];
    float ao = dbih[3*Hn + j]   + dbhh[3*Hn + j];
    const float* cp = ctx + b;
    const float* wi = WiT + j;
    const float* wg = WgT + j;
    const float* wo = WoT + j;
    #pragma unroll 4
    for (int k = 0; k < Hn; k++) {
        float cv = cp[k * Bn];
        ai += wi[k * Hn] * cv;
        ag += wg[k * Hn] * cv;
        ao += wo[k * Hn] * cv;
    }
    float cc = sigm(ai) * tanh_f(ag);
    float hh = sigm(ao) * tanh_f(cc);
    hdec[j * Bn + b] = hh;
}

// K_D: out[b][t] = out_b + sum_j out_W[j] * hdec[j][b]
__global__ __launch_bounds__(64)
void dec_out_k(const float* __restrict__ hdec, const float* __restrict__ oW,
               const float* __restrict__ ob, float* __restrict__ out, int t)
{
    const int b = blockIdx.x;
    const int tid = threadIdx.x;
    float a = 0.f;
    #pragma unroll
    for (int q = 0; q < 8; q++) {
        int j = tid + q * 64;
        a += oW[j] * hdec[j * Bn + b];
    }
    for (int off = 32; off; off >>= 1) a += __shfl_down(a, off, 64);
    if (tid == 0) out[b * Tn + t] = a + ob[0];
}

extern "C" void kernel_launch(void* const* d_in, const int* in_sizes, int n_in,
                              void* d_out, int out_size, void* d_ws, size_t ws_size,
                              hipStream_t stream) {
    const float* x    = (const float*)d_in[0];
    const float* eWih = (const float*)d_in[1];
    const float* eWhh = (const float*)d_in[2];
    const float* ebih = (const float*)d_in[3];
    const float* ebhh = (const float*)d_in[4];
    const float* aW1  = (const float*)d_in[5];
    const float* ab1  = (const float*)d_in[6];
    const float* aW2  = (const float*)d_in[7];
    const float* ab2  = (const float*)d_in[8];
    const float* aV   = (const float*)d_in[9];
    const float* abV  = (const float*)d_in[10];
    const float* dWih = (const float*)d_in[11];
    // d_in[12] = dec_Whh: unused (decoder LSTM starts from zero state every step)
    const float* dbih = (const float*)d_in[13];
    const float* dbhh = (const float*)d_in[14];
    const float* oW   = (const float*)d_in[15];
    const float* ob   = (const float*)d_in[16];
    float* out = (float*)d_out;

    float* w = (float*)d_ws;
    float* xT   = w;  w += (size_t)Sn * Fn * Bn;        // 2,097,152
    float* h0   = w;  w += Hn * Bn;
    float* h1   = w;  w += Hn * Bn;
    float* cst  = w;  w += Hn * Bn;
    float* enc  = w;  w += (size_t)Sn * Hn * Bn;        // 16,777,216
    float* w2e  = w;  w += (size_t)Bn * Sn * Un;        // 4,194,304
    float* W2T  = w;  w += Hn * Un;
    float* WiT  = w;  w += Hn * Hn;
    float* WgT  = w;  w += Hn * Hn;
    float* WoT  = w;  w += Hn * Hn;
    float* attn = w;  w += Sn * Bn;
    float* ctx  = w;  w += Hn * Bn;
    float* hdec = w;  w += Hn * Bn;

    k_transpose_x  <<<8192, 256, 0, stream>>>(x, xT);
    k_transpose_w2 <<<256,  256, 0, stream>>>(aW2, W2T);
    k_transpose_dec<<<1024, 256, 0, stream>>>(dWih, WiT, WgT, WoT);
    k_zero         <<<256,  256, 0, stream>>>(h0, cst);

    for (int t = 0; t < Sn; t++) {
        const float* hp = (t & 1) ? h1 : h0;
        float*       hn = (t & 1) ? h0 : h1;
        enc_step_k<<<256, 256, 0, stream>>>(xT, eWih, eWhh, ebih, ebhh, hp, hn, cst, enc, t);
    }
    // final encoder h lands in h0 (512 steps, even)

    w2enc_k<<<512, 256, 0, stream>>>(enc, W2T, ab2, w2e);

    for (int t = 0; t < Tn; t++) {
        const float* hatt = (t == 0) ? h0 : hdec;
        dec_attn_k<<<64,  256, 0, stream>>>(hatt, aW1, ab1, aV, abV, w2e, attn);
        dec_ctx_k <<<256, 128, 0, stream>>>(attn, enc, ctx);
        dec_gate_k<<<256, 128, 0, stream>>>(ctx, WiT, WgT, WoT, dbih, dbhh, hdec);
        dec_out_k <<<64,  64,  0, stream>>>(hdec, oW, ob, out, t);
    }
}